// Round 5
// baseline (405.282 us; speedup 1.0000x reference)
//
#include <hip/hip_runtime.h>
#include <hip/hip_bf16.h>
#include <math.h>

typedef short v4s __attribute__((ext_vector_type(4)));
typedef short v8s __attribute__((ext_vector_type(8)));
typedef float v4f __attribute__((ext_vector_type(4)));
typedef unsigned short us8 __attribute__((ext_vector_type(8)));

#if __has_builtin(__builtin_amdgcn_mfma_f32_16x16x16bf16_1k)
#define MFMA16(a, b, c) __builtin_amdgcn_mfma_f32_16x16x16bf16_1k(a, b, c, 0, 0, 0)
#else
__device__ inline v4f mfma16_fb(v4s a, v4s b, v4f c) {
    v8s a8 = {a[0], a[1], a[2], a[3], 0, 0, 0, 0};
    v8s b8 = {b[0], b[1], b[2], b[3], 0, 0, 0, 0};
    return __builtin_amdgcn_mfma_f32_16x16x32_bf16(a8, b8, c, 0, 0, 0);
}
#define MFMA16(a, b, c) mfma16_fb(a, b, c)
#endif

#define MFMA32(a, b, c) __builtin_amdgcn_mfma_f32_16x16x32_bf16(a, b, c, 0, 0, 0)

__device__ inline unsigned short f2bf(float f) {
    __hip_bfloat16 h = __float2bfloat16(f);
    union { __hip_bfloat16 h; unsigned short u; } cv;
    cv.h = h;
    return cv.u;
}

__device__ inline void gld16(const void* g, void* l) {
    __builtin_amdgcn_global_load_lds((const __attribute__((address_space(1))) void*)g,
                                     (__attribute__((address_space(3))) void*)l, 16, 0, 0);
}

// fast GELU (tanh form via sigmoid): max abs err vs exact-erf gelu ~1e-3
__device__ inline float gelu_fast(float v) {
    const float z2 = 1.5957691216057308f * (v + 0.044715f * v * v * v);  // 2*sqrt(2/pi)*(...)
    return v / (1.0f + __expf(-z2));
}

// ---------------- weight transpose + bf16 convert: in f32 [R][Cn] -> out bf16 [Cn][R]
__global__ __launch_bounds__(256) void transpose_cvt(const float* __restrict__ in,
                                                     unsigned short* __restrict__ out,
                                                     int R, int Cn) {
    __shared__ float t[32][33];
    const int tid = threadIdx.x;
    const int tx = tid & 31, ty = tid >> 5;
    const int bx = blockIdx.x, by = blockIdx.y;
#pragma unroll
    for (int i = 0; i < 4; ++i) {
        int r = by * 32 + ty + i * 8;
        int c = bx * 32 + tx;
        t[ty + i * 8][tx] = in[(size_t)r * Cn + c];
    }
    __syncthreads();
#pragma unroll
    for (int i = 0; i < 4; ++i) {
        out[(size_t)(bx * 32 + ty + i * 8) * R + by * 32 + tx] = f2bf(t[tx][ty + i * 8]);
    }
}

// ---------------- LayerNorm row kernel: f32 [rows][768] -> bf16 [rows][768]
__global__ __launch_bounds__(256) void ln_row(const float* __restrict__ x,
                                              const float* __restrict__ lw,
                                              const float* __restrict__ lb,
                                              unsigned short* __restrict__ out) {
    const int row = blockIdx.x;
    const int tid = threadIdx.x;
    const float* xr = x + (size_t)row * 768;
    float v0 = xr[tid], v1 = xr[tid + 256], v2 = xr[tid + 512];
    float s = v0 + v1 + v2;
    float q = v0 * v0 + v1 * v1 + v2 * v2;
#pragma unroll
    for (int o = 1; o < 64; o <<= 1) {
        s += __shfl_xor(s, o);
        q += __shfl_xor(q, o);
    }
    __shared__ float rs[4], rq[4];
    const int w = tid >> 6;
    if ((tid & 63) == 0) { rs[w] = s; rq[w] = q; }
    __syncthreads();
    s = rs[0] + rs[1] + rs[2] + rs[3];
    q = rq[0] + rq[1] + rq[2] + rq[3];
    const float mean = s * (1.0f / 768.0f);
    const float var = q * (1.0f / 768.0f) - mean * mean;
    const float rstd = rsqrtf(var + 1e-5f);
    unsigned short* orow = out + (size_t)row * 768;
    orow[tid] = f2bf((v0 - mean) * rstd * lw[tid] + lb[tid]);
    orow[tid + 256] = f2bf((v1 - mean) * rstd * lw[tid + 256] + lb[tid + 256]);
    orow[tid + 512] = f2bf((v2 - mean) * rstd * lw[tid + 512] + lb[tid + 512]);
}

// ---------------- GEMM: out[M][N] = A[M][K] * BT[N][K]^T + bias (+resid) (+gelu)
// EPI 0: bias -> bf16 ; EPI 1: bias + resid -> f32 ; EPI 2: bias + gelu -> bf16
template <int EPI>
__global__ __launch_bounds__(256) void gemm_bf16(const unsigned short* __restrict__ A,
                                                 const unsigned short* __restrict__ BT,
                                                 const float* __restrict__ bias,
                                                 const float* __restrict__ resid,
                                                 void* __restrict__ outp,
                                                 int M, int N, int K) {
    __shared__ __align__(16) unsigned short As[128 * 64];
    __shared__ __align__(16) unsigned short Bs[128 * 64];
    const int tid = threadIdx.x;
    const int lane = tid & 63;
    const int w = tid >> 6;
    const int g = lane >> 4;
    const int c16 = lane & 15;
    const int row0 = blockIdx.x * 128;
    const int col0 = blockIdx.y * 128;
    const int wm = w & 1, wn = w >> 1;

    v4f acc[4][4];
#pragma unroll
    for (int m = 0; m < 4; ++m)
#pragma unroll
        for (int n = 0; n < 4; ++n) acc[m][n] = (v4f){0.f, 0.f, 0.f, 0.f};

    // hoisted per-thread staging pointers (strength-reduced: += 64 elements per K-step)
    const unsigned short* ap[4];
    const unsigned short* bp[4];
#pragma unroll
    for (int i = 0; i < 4; ++i) {
        const int c = (i * 4 + w) * 64 + lane;  // 16B chunk id, 0..1023
        const int r = c >> 3;
        const int dc = (c & 7) ^ (r & 7);  // XOR-swizzled source chunk
        ap[i] = A + (size_t)(row0 + r) * K + dc * 8;
        bp[i] = BT + (size_t)(col0 + r) * K + dc * 8;
    }

    const int nk = K >> 6;
    for (int kt = 0; kt < nk; ++kt) {
        __syncthreads();  // protect previous-iteration reads
#pragma unroll
        for (int i = 0; i < 4; ++i) {
            const int c = (i * 4 + w) * 64 + lane;
            gld16(ap[i], As + (size_t)c * 8);
            gld16(bp[i], Bs + (size_t)c * 8);
            ap[i] += 64;
            bp[i] += 64;
        }
        __syncthreads();  // drains vmcnt before barrier
#pragma unroll
        for (int ks = 0; ks < 2; ++ks) {
            const int koff = ks * 64 + 16 * g;  // byte offset of this lane's 16B chunk
            v8s af[4], bf[4];
#pragma unroll
            for (int m = 0; m < 4; ++m) {
                const int r = wm * 64 + m * 16 + c16;
                af[m] = *(const v8s*)((const char*)As + r * 128 + (koff ^ ((r & 7) << 4)));
            }
#pragma unroll
            for (int n = 0; n < 4; ++n) {
                const int r = wn * 64 + n * 16 + c16;
                bf[n] = *(const v8s*)((const char*)Bs + r * 128 + (koff ^ ((r & 7) << 4)));
            }
#pragma unroll
            for (int m = 0; m < 4; ++m)
#pragma unroll
                for (int n = 0; n < 4; ++n) acc[m][n] = MFMA32(af[m], bf[n], acc[m][n]);
        }
    }
#pragma unroll
    for (int m = 0; m < 4; ++m)
#pragma unroll
        for (int n = 0; n < 4; ++n)
#pragma unroll
            for (int r = 0; r < 4; ++r) {
                const int row = row0 + wm * 64 + m * 16 + 4 * g + r;
                const int col = col0 + wn * 64 + n * 16 + c16;
                float v = acc[m][n][r] + bias[col];
                if (EPI == 1) v += resid[(size_t)row * N + col];
                if (EPI == 2) v = gelu_fast(v);
                if (EPI == 1)
                    ((float*)outp)[(size_t)row * N + col] = v;
                else
                    ((unsigned short*)outp)[(size_t)row * N + col] = f2bf(v);
            }
}

// ---------------- causal attention: qkv bf16 [8192][2304] (k|q|v) -> y bf16 [8192][768]
__global__ __launch_bounds__(256) void attn_kernel(const unsigned short* __restrict__ qkv,
                                                   unsigned short* __restrict__ y) {
    __shared__ __align__(16) unsigned short Ks[64 * 64];    // swizzled [kk][d]
    __shared__ __align__(16) unsigned short Vt[64 * 68];    // [d][kk], stride 68
    __shared__ __align__(16) unsigned short Ps[4][16 * 68]; // per-wave [q][kk], stride 68
    const int tid = threadIdx.x;
    const int lane = tid & 63;
    const int w = tid >> 6;
    const int g = lane >> 4;
    const int c16 = lane & 15;
    const int qt = gridDim.x - 1 - blockIdx.x;  // longest blocks launch first
    const int h = blockIdx.y, b = blockIdx.z;
    const int tok0 = b * 1024 + qt * 64;

    // Q fragments (B-operand of S^T): Q[q = c16 of wave's 16 rows][d]
    v4s qf[4];
    const unsigned short* qbase = qkv + (size_t)(tok0 + w * 16 + c16) * 2304 + 768 + h * 64;
#pragma unroll
    for (int ks = 0; ks < 4; ++ks) qf[ks] = *(const v4s*)(qbase + ks * 16 + 4 * g);

    v4f yacc[4];
#pragma unroll
    for (int d = 0; d < 4; ++d) yacc[d] = (v4f){0.f, 0.f, 0.f, 0.f};
    float mrun = -__builtin_inff();
    float lrun = 0.0f;
    const int qpos = qt * 64 + w * 16 + c16;  // my softmax column's position

    for (int kt = 0; kt <= qt; ++kt) {
        const int tokk = b * 1024 + kt * 64;
        __syncthreads();
        // stage K (swizzled) via global_load_lds: 512 chunks
#pragma unroll
        for (int i = 0; i < 2; ++i) {
            const int c = (i * 4 + w) * 64 + lane;
            const int kk = c >> 3;
            const int dc = (c & 7) ^ (kk & 7);
            gld16(qkv + (size_t)(tokk + kk) * 2304 + h * 64 + dc * 8, Ks + (size_t)c * 8);
        }
        // stage V transposed ([d][kk]) via registers
#pragma unroll
        for (int it = 0; it < 2; ++it) {
            const int off = (it * 256 + tid) * 8;
            const int kk = off >> 6, d0 = off & 63;
            us8 vv = *(const us8*)(qkv + (size_t)(tokk + kk) * 2304 + 1536 + h * 64 + d0);
#pragma unroll
            for (int j = 0; j < 8; ++j) Vt[(d0 + j) * 68 + kk] = vv[j];
        }
        __syncthreads();

        // S^T = K * Q^T (A = K rows, B = Q^T) -> st[kb][r] = S^T[kb*16+4g+r][q=c16]
        v4f st[4];
#pragma unroll
        for (int kb = 0; kb < 4; ++kb) st[kb] = (v4f){0.f, 0.f, 0.f, 0.f};
#pragma unroll
        for (int ks = 0; ks < 4; ++ks) {
            const int koff = ks * 32 + 8 * g;
            v4s kf[4];
#pragma unroll
            for (int kb = 0; kb < 4; ++kb) {
                const int r = kb * 16 + c16;
                kf[kb] = *(const v4s*)((const char*)Ks + r * 128 + (koff ^ ((r & 7) << 4)));
            }
#pragma unroll
            for (int kb = 0; kb < 4; ++kb) st[kb] = MFMA16(kf[kb], qf[ks], st[kb]);
        }

        // causal mask (diagonal tile only) + online softmax (per column q = c16)
        float pmax = -__builtin_inff();
        if (kt == qt) {
#pragma unroll
            for (int kb = 0; kb < 4; ++kb)
#pragma unroll
                for (int r = 0; r < 4; ++r) {
                    const int kkpos = kt * 64 + kb * 16 + 4 * g + r;
                    if (kkpos > qpos) st[kb][r] = -__builtin_inff();
                    pmax = fmaxf(pmax, st[kb][r]);
                }
        } else {
#pragma unroll
            for (int kb = 0; kb < 4; ++kb)
#pragma unroll
                for (int r = 0; r < 4; ++r) pmax = fmaxf(pmax, st[kb][r]);
        }
        pmax = fmaxf(pmax, __shfl_xor(pmax, 16));
        pmax = fmaxf(pmax, __shfl_xor(pmax, 32));
        const float mnew = fmaxf(mrun, pmax);
        const float scale = __expf(mrun - mnew);  // exp(-inf) = 0 on first tile
        float psum = 0.0f;
#pragma unroll
        for (int kb = 0; kb < 4; ++kb) {
            v4s pw;
#pragma unroll
            for (int r = 0; r < 4; ++r) {
                const float pv = __expf(st[kb][r] - mnew);  // masked -> exp(-inf)=0
                psum += pv;
                pw[r] = (short)f2bf(pv);
            }
            *(v4s*)((char*)&Ps[w][0] + c16 * 136 + kb * 32 + 8 * g) = pw;
        }
        psum += __shfl_xor(psum, 16);
        psum += __shfl_xor(psum, 32);
        lrun = lrun * scale + psum;
        mrun = mnew;

        // rescale accumulator (rows live as q = 4g + r)
        float scr[4];
#pragma unroll
        for (int r = 0; r < 4; ++r) scr[r] = __shfl(scale, g * 4 + r);
#pragma unroll
        for (int d = 0; d < 4; ++d)
#pragma unroll
            for (int r = 0; r < 4; ++r) yacc[d][r] *= scr[r];

        // y += P * V
#pragma unroll
        for (int ks = 0; ks < 4; ++ks) {
            const v4s pf = *(const v4s*)((const char*)&Ps[w][0] + c16 * 136 + ks * 32 + 8 * g);
#pragma unroll
            for (int d = 0; d < 4; ++d) {
                const v4s vf =
                    *(const v4s*)((const char*)Vt + (d * 16 + c16) * 136 + ks * 32 + 8 * g);
                yacc[d] = MFMA16(pf, vf, yacc[d]);
            }
        }
    }

    const float inv = 1.0f / lrun;
    float invr[4];
#pragma unroll
    for (int r = 0; r < 4; ++r) invr[r] = __shfl(inv, g * 4 + r);
#pragma unroll
    for (int d = 0; d < 4; ++d)
#pragma unroll
        for (int r = 0; r < 4; ++r) {
            const int row = tok0 + w * 16 + 4 * g + r;
            const int col = h * 64 + d * 16 + c16;
            y[(size_t)row * 768 + col] = f2bf(yacc[d][r] * invr[r]);
        }
}

extern "C" void kernel_launch(void* const* d_in, const int* in_sizes, int n_in,
                              void* d_out, int out_size, void* d_ws, size_t ws_size,
                              hipStream_t stream) {
    const float* x = (const float*)d_in[0];
    const float* ln_w = (const float*)d_in[1];
    const float* ln_b = (const float*)d_in[2];
    const float* w_qkv = (const float*)d_in[3];
    const float* b_qkv = (const float*)d_in[4];
    const float* w_out = (const float*)d_in[5];
    const float* b_out = (const float*)d_in[6];
    const float* w_c1 = (const float*)d_in[7];
    const float* b_c1 = (const float*)d_in[8];
    const float* w_c2 = (const float*)d_in[9];
    const float* b_c2 = (const float*)d_in[10];
    float* out = (float*)d_out;

    char* ws = (char*)d_ws;
    unsigned short* wTqkv = (unsigned short*)(ws + 0);          // [2304][768]
    unsigned short* wTout = (unsigned short*)(ws + 3538944);    // [768][768]
    unsigned short* wTc1 = (unsigned short*)(ws + 4718592);     // [3072][768]
    unsigned short* wTc2 = (unsigned short*)(ws + 9437184);     // [768][3072]
    unsigned short* hbuf = (unsigned short*)(ws + 14155776);    // [8192][768] bf16 (h, then h2)
    unsigned short* qkvb = (unsigned short*)(ws + 26738688);    // [8192][2304] bf16
    unsigned short* ybuf = (unsigned short*)(ws + 64487424);    // [8192][768] bf16
    float* x2 = (float*)(ws + 77070336);                        // [8192][768] f32
    unsigned short* m1 = qkvb;  // reuse qkv+y region: [8192][3072] bf16

    transpose_cvt<<<dim3(2304 / 32, 768 / 32), 256, 0, stream>>>(w_qkv, wTqkv, 768, 2304);
    transpose_cvt<<<dim3(768 / 32, 768 / 32), 256, 0, stream>>>(w_out, wTout, 768, 768);
    transpose_cvt<<<dim3(3072 / 32, 768 / 32), 256, 0, stream>>>(w_c1, wTc1, 768, 3072);
    transpose_cvt<<<dim3(768 / 32, 3072 / 32), 256, 0, stream>>>(w_c2, wTc2, 3072, 768);

    ln_row<<<8192, 256, 0, stream>>>(x, ln_w, ln_b, hbuf);
    gemm_bf16<0><<<dim3(64, 18), 256, 0, stream>>>(hbuf, wTqkv, b_qkv, nullptr, qkvb, 8192, 2304, 768);
    attn_kernel<<<dim3(16, 12, 8), 256, 0, stream>>>(qkvb, ybuf);
    gemm_bf16<1><<<dim3(64, 6), 256, 0, stream>>>(ybuf, wTout, b_out, x, x2, 8192, 768, 768);
    ln_row<<<8192, 256, 0, stream>>>(x2, ln_w, ln_b, hbuf);
    gemm_bf16<2><<<dim3(64, 24), 256, 0, stream>>>(hbuf, wTc1, b_c1, nullptr, m1, 8192, 3072, 768);
    gemm_bf16<1><<<dim3(64, 6), 256, 0, stream>>>(m1, wTc2, b_c2, x2, out, 8192, 768, 3072);
}

// Round 6
// 367.067 us; speedup vs baseline: 1.1041x; 1.1041x over previous
//
#include <hip/hip_runtime.h>
#include <hip/hip_bf16.h>
#include <math.h>

typedef short v4s __attribute__((ext_vector_type(4)));
typedef short v8s __attribute__((ext_vector_type(8)));
typedef float v4f __attribute__((ext_vector_type(4)));
typedef unsigned short us8 __attribute__((ext_vector_type(8)));

#if __has_builtin(__builtin_amdgcn_mfma_f32_16x16x16bf16_1k)
#define MFMA16(a, b, c) __builtin_amdgcn_mfma_f32_16x16x16bf16_1k(a, b, c, 0, 0, 0)
#else
__device__ inline v4f mfma16_fb(v4s a, v4s b, v4f c) {
    v8s a8 = {a[0], a[1], a[2], a[3], 0, 0, 0, 0};
    v8s b8 = {b[0], b[1], b[2], b[3], 0, 0, 0, 0};
    return __builtin_amdgcn_mfma_f32_16x16x32_bf16(a8, b8, c, 0, 0, 0);
}
#define MFMA16(a, b, c) mfma16_fb(a, b, c)
#endif

#define MFMA32(a, b, c) __builtin_amdgcn_mfma_f32_16x16x32_bf16(a, b, c, 0, 0, 0)

__device__ inline unsigned short f2bf(float f) {
    __hip_bfloat16 h = __float2bfloat16(f);
    union { __hip_bfloat16 h; unsigned short u; } cv;
    cv.h = h;
    return cv.u;
}

__device__ inline void gld16(const void* g, void* l) {
    __builtin_amdgcn_global_load_lds((const __attribute__((address_space(1))) void*)g,
                                     (__attribute__((address_space(3))) void*)l, 16, 0, 0);
}

// fast GELU (tanh form via sigmoid): max abs err vs exact-erf gelu ~1e-3
__device__ inline float gelu_fast(float v) {
    const float z2 = 1.5957691216057308f * (v + 0.044715f * v * v * v);
    return v / (1.0f + __expf(-z2));
}

// ---------------- weight transpose + bf16 convert: in f32 [R][Cn] -> out bf16 [Cn][R]
__global__ __launch_bounds__(256) void transpose_cvt(const float* __restrict__ in,
                                                     unsigned short* __restrict__ out,
                                                     int R, int Cn) {
    __shared__ float t[32][33];
    const int tid = threadIdx.x;
    const int tx = tid & 31, ty = tid >> 5;
    const int bx = blockIdx.x, by = blockIdx.y;
#pragma unroll
    for (int i = 0; i < 4; ++i) {
        int r = by * 32 + ty + i * 8;
        int c = bx * 32 + tx;
        t[ty + i * 8][tx] = in[(size_t)r * Cn + c];
    }
    __syncthreads();
#pragma unroll
    for (int i = 0; i < 4; ++i) {
        out[(size_t)(bx * 32 + ty + i * 8) * R + by * 32 + tx] = f2bf(t[tx][ty + i * 8]);
    }
}

// ---------------- LayerNorm row kernel: f32 [rows][768] -> bf16 [rows][768]
__global__ __launch_bounds__(256) void ln_row(const float* __restrict__ x,
                                              const float* __restrict__ lw,
                                              const float* __restrict__ lb,
                                              unsigned short* __restrict__ out) {
    const int row = blockIdx.x;
    const int tid = threadIdx.x;
    const float* xr = x + (size_t)row * 768;
    float v0 = xr[tid], v1 = xr[tid + 256], v2 = xr[tid + 512];
    float s = v0 + v1 + v2;
    float q = v0 * v0 + v1 * v1 + v2 * v2;
#pragma unroll
    for (int o = 1; o < 64; o <<= 1) {
        s += __shfl_xor(s, o);
        q += __shfl_xor(q, o);
    }
    __shared__ float rs[4], rq[4];
    const int w = tid >> 6;
    if ((tid & 63) == 0) { rs[w] = s; rq[w] = q; }
    __syncthreads();
    s = rs[0] + rs[1] + rs[2] + rs[3];
    q = rq[0] + rq[1] + rq[2] + rq[3];
    const float mean = s * (1.0f / 768.0f);
    const float var = q * (1.0f / 768.0f) - mean * mean;
    const float rstd = rsqrtf(var + 1e-5f);
    unsigned short* orow = out + (size_t)row * 768;
    orow[tid] = f2bf((v0 - mean) * rstd * lw[tid] + lb[tid]);
    orow[tid + 256] = f2bf((v1 - mean) * rstd * lw[tid + 256] + lb[tid + 256]);
    orow[tid + 512] = f2bf((v2 - mean) * rstd * lw[tid + 512] + lb[tid + 512]);
}

// ---------------- GEMM: out[M][N] = A[M][K] * BT[N][K]^T + bias (+resid) (+gelu)
// EPI 0: bias -> bf16 ; EPI 1: bias + resid -> f32 ; EPI 2: bias + gelu -> bf16
template <int EPI>
__global__ __launch_bounds__(256) void gemm_bf16(const unsigned short* __restrict__ A,
                                                 const unsigned short* __restrict__ BT,
                                                 const float* __restrict__ bias,
                                                 const float* __restrict__ resid,
                                                 void* __restrict__ outp,
                                                 int M, int N, int K) {
    __shared__ __align__(16) unsigned short As[128 * 64];
    __shared__ __align__(16) unsigned short Bs[128 * 64];
    const int tid = threadIdx.x;
    const int lane = tid & 63;
    const int w = tid >> 6;
    const int g = lane >> 4;
    const int c16 = lane & 15;
    const int row0 = blockIdx.x * 128;
    const int col0 = blockIdx.y * 128;
    const int wm = w & 1, wn = w >> 1;

    v4f acc[4][4];
#pragma unroll
    for (int m = 0; m < 4; ++m)
#pragma unroll
        for (int n = 0; n < 4; ++n) acc[m][n] = (v4f){0.f, 0.f, 0.f, 0.f};

    const unsigned short* ap[4];
    const unsigned short* bp[4];
#pragma unroll
    for (int i = 0; i < 4; ++i) {
        const int c = (i * 4 + w) * 64 + lane;  // 16B chunk id, 0..1023
        const int r = c >> 3;
        const int dc = (c & 7) ^ (r & 7);  // XOR-swizzled source chunk
        ap[i] = A + (size_t)(row0 + r) * K + dc * 8;
        bp[i] = BT + (size_t)(col0 + r) * K + dc * 8;
    }

    const int nk = K >> 6;
    for (int kt = 0; kt < nk; ++kt) {
        __syncthreads();  // protect previous-iteration reads
#pragma unroll
        for (int i = 0; i < 4; ++i) {
            const int c = (i * 4 + w) * 64 + lane;
            gld16(ap[i], As + (size_t)c * 8);
            gld16(bp[i], Bs + (size_t)c * 8);
            ap[i] += 64;
            bp[i] += 64;
        }
        __syncthreads();  // drains vmcnt before barrier
#pragma unroll
        for (int ks = 0; ks < 2; ++ks) {
            const int koff = ks * 64 + 16 * g;  // byte offset of this lane's 16B chunk
            v8s af[4], bf[4];
#pragma unroll
            for (int m = 0; m < 4; ++m) {
                const int r = wm * 64 + m * 16 + c16;
                af[m] = *(const v8s*)((const char*)As + r * 128 + (koff ^ ((r & 7) << 4)));
            }
#pragma unroll
            for (int n = 0; n < 4; ++n) {
                const int r = wn * 64 + n * 16 + c16;
                bf[n] = *(const v8s*)((const char*)Bs + r * 128 + (koff ^ ((r & 7) << 4)));
            }
#pragma unroll
            for (int m = 0; m < 4; ++m)
#pragma unroll
                for (int n = 0; n < 4; ++n) acc[m][n] = MFMA32(af[m], bf[n], acc[m][n]);
        }
    }
#pragma unroll
    for (int m = 0; m < 4; ++m)
#pragma unroll
        for (int n = 0; n < 4; ++n)
#pragma unroll
            for (int r = 0; r < 4; ++r) {
                const int row = row0 + wm * 64 + m * 16 + 4 * g + r;
                const int col = col0 + wn * 64 + n * 16 + c16;
                float v = acc[m][n][r] + bias[col];
                if (EPI == 1) v += resid[(size_t)row * N + col];
                if (EPI == 2) v = gelu_fast(v);
                if (EPI == 1)
                    ((float*)outp)[(size_t)row * N + col] = v;
                else
                    ((unsigned short*)outp)[(size_t)row * N + col] = f2bf(v);
            }
}

// ---------------- attention tile compute: S^T = K*Q^T (x32), online softmax, y += P*V
__device__ inline void attn_tile(const unsigned short* Ks, const unsigned short* Vt,
                                 unsigned short* Psw, const v8s* qf8, v4f* yacc,
                                 float& mrun, float& lrun, bool diag, int mask0,
                                 int g, int c16) {
    v4f st[4];
#pragma unroll
    for (int kb = 0; kb < 4; ++kb) st[kb] = (v4f){0.f, 0.f, 0.f, 0.f};
#pragma unroll
    for (int ks = 0; ks < 2; ++ks) {
        const int koff = ks * 64 + 16 * g;
#pragma unroll
        for (int kb = 0; kb < 4; ++kb) {
            const int r = kb * 16 + c16;
            const v8s kf = *(const v8s*)((const char*)Ks + r * 128 + (koff ^ ((r & 7) << 4)));
            st[kb] = MFMA32(kf, qf8[ks], st[kb]);
        }
    }

    float pmax = -__builtin_inff();
    if (diag) {
#pragma unroll
        for (int kb = 0; kb < 4; ++kb)
#pragma unroll
            for (int r = 0; r < 4; ++r) {
                if (kb * 16 + 4 * g + r > mask0) st[kb][r] = -__builtin_inff();
                pmax = fmaxf(pmax, st[kb][r]);
            }
    } else {
#pragma unroll
        for (int kb = 0; kb < 4; ++kb)
#pragma unroll
            for (int r = 0; r < 4; ++r) pmax = fmaxf(pmax, st[kb][r]);
    }
    pmax = fmaxf(pmax, __shfl_xor(pmax, 16));
    pmax = fmaxf(pmax, __shfl_xor(pmax, 32));
    const float mnew = fmaxf(mrun, pmax);
    const float scale = __expf(mrun - mnew);
    float psum = 0.0f;
#pragma unroll
    for (int kb = 0; kb < 4; ++kb) {
        v4s pw;
#pragma unroll
        for (int r = 0; r < 4; ++r) {
            const float pv = __expf(st[kb][r] - mnew);
            psum += pv;
            pw[r] = (short)f2bf(pv);
        }
        *(v4s*)((char*)Psw + c16 * 136 + kb * 32 + 8 * g) = pw;
    }
    psum += __shfl_xor(psum, 16);
    psum += __shfl_xor(psum, 32);
    lrun = lrun * scale + psum;
    mrun = mnew;

    float scr[4];
#pragma unroll
    for (int r = 0; r < 4; ++r) scr[r] = __shfl(scale, g * 4 + r);
#pragma unroll
    for (int d = 0; d < 4; ++d)
#pragma unroll
        for (int r = 0; r < 4; ++r) yacc[d][r] *= scr[r];

#pragma unroll
    for (int ks = 0; ks < 4; ++ks) {
        const v4s pf = *(const v4s*)((const char*)Psw + c16 * 136 + ks * 32 + 8 * g);
#pragma unroll
        for (int d = 0; d < 4; ++d) {
            const v4s vf = *(const v4s*)((const char*)Vt + (d * 16 + c16) * 136 + ks * 32 + 8 * g);
            yacc[d] = MFMA16(pf, vf, yacc[d]);
        }
    }
}

// ---------------- causal attention: qkv bf16 [8192][2304] (k|q|v) -> y bf16 [8192][768]
// fold-paired: block p handles q-tiles qtA=15-p and qtB=p; K/V tiles staged ONCE (B's range
// is a subset of A's). 768 balanced blocks (3/CU), 16-p staging iters each.
__global__ __launch_bounds__(256) void attn_kernel(const unsigned short* __restrict__ qkv,
                                                   unsigned short* __restrict__ y) {
    __shared__ __align__(16) unsigned short Ks[64 * 64];    // swizzled [kk][d]
    __shared__ __align__(16) unsigned short Vt[64 * 68];    // [d][kk], stride 68
    __shared__ __align__(16) unsigned short Ps[4][16 * 68]; // per-wave [q][kk], stride 68
    const int tid = threadIdx.x;
    const int lane = tid & 63;
    const int w = tid >> 6;
    const int g = lane >> 4;
    const int c16 = lane & 15;
    const int p = blockIdx.x;  // 0..7
    const int h = blockIdx.y, b = blockIdx.z;
    const int qtA = 15 - p, qtB = p;
    const int tokA = b * 1024 + qtA * 64;
    const int tokB = b * 1024 + qtB * 64;

    v8s qfA[2], qfB[2];
    {
        const unsigned short* qbA = qkv + (size_t)(tokA + w * 16 + c16) * 2304 + 768 + h * 64;
        const unsigned short* qbB = qkv + (size_t)(tokB + w * 16 + c16) * 2304 + 768 + h * 64;
#pragma unroll
        for (int ks = 0; ks < 2; ++ks) {
            qfA[ks] = *(const v8s*)(qbA + ks * 32 + 8 * g);
            qfB[ks] = *(const v8s*)(qbB + ks * 32 + 8 * g);
        }
    }

    v4f yA[4], yB[4];
#pragma unroll
    for (int d = 0; d < 4; ++d) {
        yA[d] = (v4f){0.f, 0.f, 0.f, 0.f};
        yB[d] = (v4f){0.f, 0.f, 0.f, 0.f};
    }
    float mA = -__builtin_inff(), lA = 0.0f;
    float mB = -__builtin_inff(), lB = 0.0f;
    const int qrow = w * 16 + c16;  // my softmax column's row-in-tile

    for (int kt = 0; kt <= qtA; ++kt) {
        const int tokk = b * 1024 + kt * 64;
        __syncthreads();
        // stage K (swizzled) via global_load_lds: 512 chunks
#pragma unroll
        for (int i = 0; i < 2; ++i) {
            const int c = (i * 4 + w) * 64 + lane;
            const int kk = c >> 3;
            const int dc = (c & 7) ^ (kk & 7);
            gld16(qkv + (size_t)(tokk + kk) * 2304 + h * 64 + dc * 8, Ks + (size_t)c * 8);
        }
        // stage V transposed ([d][kk]) via registers
#pragma unroll
        for (int it = 0; it < 2; ++it) {
            const int off = (it * 256 + tid) * 8;
            const int kk = off >> 6, d0 = off & 63;
            us8 vv = *(const us8*)(qkv + (size_t)(tokk + kk) * 2304 + 1536 + h * 64 + d0);
#pragma unroll
            for (int j = 0; j < 8; ++j) Vt[(d0 + j) * 68 + kk] = vv[j];
        }
        __syncthreads();

        attn_tile(Ks, Vt, &Ps[w][0], qfA, yA, mA, lA, kt == qtA, qrow, g, c16);
        if (kt <= qtB)
            attn_tile(Ks, Vt, &Ps[w][0], qfB, yB, mB, lB, kt == qtB, qrow, g, c16);
    }

    {
        const float inv = 1.0f / lA;
        float invr[4];
#pragma unroll
        for (int r = 0; r < 4; ++r) invr[r] = __shfl(inv, g * 4 + r);
#pragma unroll
        for (int d = 0; d < 4; ++d)
#pragma unroll
            for (int r = 0; r < 4; ++r) {
                const int row = tokA + w * 16 + 4 * g + r;
                const int col = h * 64 + d * 16 + c16;
                y[(size_t)row * 768 + col] = f2bf(yA[d][r] * invr[r]);
            }
    }
    {
        const float inv = 1.0f / lB;
        float invr[4];
#pragma unroll
        for (int r = 0; r < 4; ++r) invr[r] = __shfl(inv, g * 4 + r);
#pragma unroll
        for (int d = 0; d < 4; ++d)
#pragma unroll
            for (int r = 0; r < 4; ++r) {
                const int row = tokB + w * 16 + 4 * g + r;
                const int col = h * 64 + d * 16 + c16;
                y[(size_t)row * 768 + col] = f2bf(yB[d][r] * invr[r]);
            }
    }
}

extern "C" void kernel_launch(void* const* d_in, const int* in_sizes, int n_in,
                              void* d_out, int out_size, void* d_ws, size_t ws_size,
                              hipStream_t stream) {
    const float* x = (const float*)d_in[0];
    const float* ln_w = (const float*)d_in[1];
    const float* ln_b = (const float*)d_in[2];
    const float* w_qkv = (const float*)d_in[3];
    const float* b_qkv = (const float*)d_in[4];
    const float* w_out = (const float*)d_in[5];
    const float* b_out = (const float*)d_in[6];
    const float* w_c1 = (const float*)d_in[7];
    const float* b_c1 = (const float*)d_in[8];
    const float* w_c2 = (const float*)d_in[9];
    const float* b_c2 = (const float*)d_in[10];
    float* out = (float*)d_out;

    char* ws = (char*)d_ws;
    unsigned short* wTqkv = (unsigned short*)(ws + 0);          // [2304][768]
    unsigned short* wTout = (unsigned short*)(ws + 3538944);    // [768][768]
    unsigned short* wTc1 = (unsigned short*)(ws + 4718592);     // [3072][768]
    unsigned short* wTc2 = (unsigned short*)(ws + 9437184);     // [768][3072]
    unsigned short* hbuf = (unsigned short*)(ws + 14155776);    // [8192][768] bf16 (h, then h2)
    unsigned short* qkvb = (unsigned short*)(ws + 26738688);    // [8192][2304] bf16
    unsigned short* ybuf = (unsigned short*)(ws + 64487424);    // [8192][768] bf16
    float* x2 = (float*)(ws + 77070336);                        // [8192][768] f32
    unsigned short* m1 = qkvb;  // reuse qkv+y region: [8192][3072] bf16

    transpose_cvt<<<dim3(2304 / 32, 768 / 32), 256, 0, stream>>>(w_qkv, wTqkv, 768, 2304);
    transpose_cvt<<<dim3(768 / 32, 768 / 32), 256, 0, stream>>>(w_out, wTout, 768, 768);
    transpose_cvt<<<dim3(3072 / 32, 768 / 32), 256, 0, stream>>>(w_c1, wTc1, 768, 3072);
    transpose_cvt<<<dim3(768 / 32, 3072 / 32), 256, 0, stream>>>(w_c2, wTc2, 3072, 768);

    ln_row<<<8192, 256, 0, stream>>>(x, ln_w, ln_b, hbuf);
    gemm_bf16<0><<<dim3(64, 18), 256, 0, stream>>>(hbuf, wTqkv, b_qkv, nullptr, qkvb, 8192, 2304, 768);
    attn_kernel<<<dim3(8, 12, 8), 256, 0, stream>>>(qkvb, ybuf);
    gemm_bf16<1><<<dim3(64, 6), 256, 0, stream>>>(ybuf, wTout, b_out, x, x2, 8192, 768, 768);
    ln_row<<<8192, 256, 0, stream>>>(x2, ln_w, ln_b, hbuf);
    gemm_bf16<2><<<dim3(64, 24), 256, 0, stream>>>(hbuf, wTc1, b_c1, nullptr, m1, 8192, 3072, 768);
    gemm_bf16<1><<<dim3(64, 6), 256, 0, stream>>>(m1, wTc2, b_c2, x2, out, 8192, 768, 3072);
}

// Round 8
// 351.126 us; speedup vs baseline: 1.1542x; 1.0454x over previous
//
#include <hip/hip_runtime.h>
#include <hip/hip_bf16.h>
#include <math.h>

typedef short v4s __attribute__((ext_vector_type(4)));
typedef short v8s __attribute__((ext_vector_type(8)));
typedef float v4f __attribute__((ext_vector_type(4)));
typedef unsigned short us8 __attribute__((ext_vector_type(8)));

#if __has_builtin(__builtin_amdgcn_mfma_f32_16x16x16bf16_1k)
#define MFMA16(a, b, c) __builtin_amdgcn_mfma_f32_16x16x16bf16_1k(a, b, c, 0, 0, 0)
#else
__device__ inline v4f mfma16_fb(v4s a, v4s b, v4f c) {
    v8s a8 = {a[0], a[1], a[2], a[3], 0, 0, 0, 0};
    v8s b8 = {b[0], b[1], b[2], b[3], 0, 0, 0, 0};
    return __builtin_amdgcn_mfma_f32_16x16x32_bf16(a8, b8, c, 0, 0, 0);
}
#define MFMA16(a, b, c) mfma16_fb(a, b, c)
#endif

#define MFMA32(a, b, c) __builtin_amdgcn_mfma_f32_16x16x32_bf16(a, b, c, 0, 0, 0)

__device__ inline unsigned short f2bf(float f) {
    __hip_bfloat16 h = __float2bfloat16(f);
    union { __hip_bfloat16 h; unsigned short u; } cv;
    cv.h = h;
    return cv.u;
}

__device__ inline void gld16(const void* g, void* l) {
    __builtin_amdgcn_global_load_lds((const __attribute__((address_space(1))) void*)g,
                                     (__attribute__((address_space(3))) void*)l, 16, 0, 0);
}

// fast GELU (tanh form via sigmoid): max abs err vs exact-erf gelu ~1e-3
__device__ inline float gelu_fast(float v) {
    const float z2 = 1.5957691216057308f * (v + 0.044715f * v * v * v);
    return v / (1.0f + __expf(-z2));
}

// ---------------- weight transpose + bf16 convert: in f32 [R][Cn] -> out bf16 [Cn][R]
__global__ __launch_bounds__(256) void transpose_cvt(const float* __restrict__ in,
                                                     unsigned short* __restrict__ out,
                                                     int R, int Cn) {
    __shared__ float t[32][33];
    const int tid = threadIdx.x;
    const int tx = tid & 31, ty = tid >> 5;
    const int bx = blockIdx.x, by = blockIdx.y;
#pragma unroll
    for (int i = 0; i < 4; ++i) {
        int r = by * 32 + ty + i * 8;
        int c = bx * 32 + tx;
        t[ty + i * 8][tx] = in[(size_t)r * Cn + c];
    }
    __syncthreads();
#pragma unroll
    for (int i = 0; i < 4; ++i) {
        out[(size_t)(bx * 32 + ty + i * 8) * R + by * 32 + tx] = f2bf(t[tx][ty + i * 8]);
    }
}

// ---------------- LayerNorm row kernel: f32 [rows][768] -> bf16 [rows][768]
__global__ __launch_bounds__(256) void ln_row(const float* __restrict__ x,
                                              const float* __restrict__ lw,
                                              const float* __restrict__ lb,
                                              unsigned short* __restrict__ out) {
    const int row = blockIdx.x;
    const int tid = threadIdx.x;
    const float* xr = x + (size_t)row * 768;
    float v0 = xr[tid], v1 = xr[tid + 256], v2 = xr[tid + 512];
    float s = v0 + v1 + v2;
    float q = v0 * v0 + v1 * v1 + v2 * v2;
#pragma unroll
    for (int o = 1; o < 64; o <<= 1) {
        s += __shfl_xor(s, o);
        q += __shfl_xor(q, o);
    }
    __shared__ float rs[4], rq[4];
    const int w = tid >> 6;
    if ((tid & 63) == 0) { rs[w] = s; rq[w] = q; }
    __syncthreads();
    s = rs[0] + rs[1] + rs[2] + rs[3];
    q = rq[0] + rq[1] + rq[2] + rq[3];
    const float mean = s * (1.0f / 768.0f);
    const float var = q * (1.0f / 768.0f) - mean * mean;
    const float rstd = rsqrtf(var + 1e-5f);
    unsigned short* orow = out + (size_t)row * 768;
    orow[tid] = f2bf((v0 - mean) * rstd * lw[tid] + lb[tid]);
    orow[tid + 256] = f2bf((v1 - mean) * rstd * lw[tid + 256] + lb[tid + 256]);
    orow[tid + 512] = f2bf((v2 - mean) * rstd * lw[tid + 512] + lb[tid + 512]);
}

// ---------------- GEMM: out[M][N] = A[M][K] * BT[N][K]^T + bias (+resid) (+gelu)
// EPI 0: bias -> bf16 ; EPI 1: bias + resid -> f32 ; EPI 2: bias + gelu -> bf16
template <int EPI>
__global__ __launch_bounds__(256) void gemm_bf16(const unsigned short* __restrict__ A,
                                                 const unsigned short* __restrict__ BT,
                                                 const float* __restrict__ bias,
                                                 const float* __restrict__ resid,
                                                 void* __restrict__ outp,
                                                 int M, int N, int K) {
    __shared__ __align__(16) unsigned short As[128 * 64];
    __shared__ __align__(16) unsigned short Bs[128 * 64];
    const int tid = threadIdx.x;
    const int lane = tid & 63;
    const int w = tid >> 6;
    const int g = lane >> 4;
    const int c16 = lane & 15;
    const int row0 = blockIdx.x * 128;
    const int col0 = blockIdx.y * 128;
    const int wm = w & 1, wn = w >> 1;

    v4f acc[4][4];
#pragma unroll
    for (int m = 0; m < 4; ++m)
#pragma unroll
        for (int n = 0; n < 4; ++n) acc[m][n] = (v4f){0.f, 0.f, 0.f, 0.f};

    const unsigned short* ap[4];
    const unsigned short* bp[4];
#pragma unroll
    for (int i = 0; i < 4; ++i) {
        const int c = (i * 4 + w) * 64 + lane;  // 16B chunk id, 0..1023
        const int r = c >> 3;
        const int dc = (c & 7) ^ (r & 7);  // XOR-swizzled source chunk
        ap[i] = A + (size_t)(row0 + r) * K + dc * 8;
        bp[i] = BT + (size_t)(col0 + r) * K + dc * 8;
    }

    const int nk = K >> 6;
    for (int kt = 0; kt < nk; ++kt) {
        __syncthreads();  // protect previous-iteration reads
#pragma unroll
        for (int i = 0; i < 4; ++i) {
            const int c = (i * 4 + w) * 64 + lane;
            gld16(ap[i], As + (size_t)c * 8);
            gld16(bp[i], Bs + (size_t)c * 8);
            ap[i] += 64;
            bp[i] += 64;
        }
        __syncthreads();  // drains vmcnt before barrier
#pragma unroll
        for (int ks = 0; ks < 2; ++ks) {
            const int koff = ks * 64 + 16 * g;  // byte offset of this lane's 16B chunk
            v8s af[4], bf[4];
#pragma unroll
            for (int m = 0; m < 4; ++m) {
                const int r = wm * 64 + m * 16 + c16;
                af[m] = *(const v8s*)((const char*)As + r * 128 + (koff ^ ((r & 7) << 4)));
            }
#pragma unroll
            for (int n = 0; n < 4; ++n) {
                const int r = wn * 64 + n * 16 + c16;
                bf[n] = *(const v8s*)((const char*)Bs + r * 128 + (koff ^ ((r & 7) << 4)));
            }
#pragma unroll
            for (int m = 0; m < 4; ++m)
#pragma unroll
                for (int n = 0; n < 4; ++n) acc[m][n] = MFMA32(af[m], bf[n], acc[m][n]);
        }
    }
#pragma unroll
    for (int m = 0; m < 4; ++m)
#pragma unroll
        for (int n = 0; n < 4; ++n)
#pragma unroll
            for (int r = 0; r < 4; ++r) {
                const int row = row0 + wm * 64 + m * 16 + 4 * g + r;
                const int col = col0 + wn * 64 + n * 16 + c16;
                float v = acc[m][n][r] + bias[col];
                if (EPI == 1) v += resid[(size_t)row * N + col];
                if (EPI == 2) v = gelu_fast(v);
                if (EPI == 1)
                    ((float*)outp)[(size_t)row * N + col] = v;
                else
                    ((unsigned short*)outp)[(size_t)row * N + col] = f2bf(v);
            }
}

// ---------------- attention tile compute: S^T = K*Q^T (x32), online softmax, y += P*V
// P stays in registers: lane (c16,g) holds P[q=c16][k=kb*16+4g+r] which IS the x16 PV
// A-fragment (A[row=l&15][k=4g+j]). No LDS round-trip for P.
__device__ inline void attn_tile(const unsigned short* Ks, const unsigned short* Vt,
                                 const v8s* qf8, v4f* yacc,
                                 float& mrun, float& lrun, bool diag, int qrow,
                                 int w, int g, int c16) {
    v4f st[4];
#pragma unroll
    for (int kb = 0; kb < 4; ++kb) st[kb] = (v4f){0.f, 0.f, 0.f, 0.f};
#pragma unroll
    for (int ks = 0; ks < 2; ++ks) {
        const int koff = ks * 64 + 16 * g;
#pragma unroll
        for (int kb = 0; kb < 4; ++kb) {
            if (diag && kb > w) continue;  // fully-masked 16-row block on diagonal tile
            const int r = kb * 16 + c16;
            const v8s kf = *(const v8s*)((const char*)Ks + r * 128 + (koff ^ ((r & 7) << 4)));
            st[kb] = MFMA32(kf, qf8[ks], st[kb]);
        }
    }

    float pmax = -__builtin_inff();
    if (diag) {
#pragma unroll
        for (int kb = 0; kb < 4; ++kb)
#pragma unroll
            for (int r = 0; r < 4; ++r) {
                if (kb > w || kb * 16 + 4 * g + r > qrow) st[kb][r] = -__builtin_inff();
                pmax = fmaxf(pmax, st[kb][r]);
            }
    } else {
#pragma unroll
        for (int kb = 0; kb < 4; ++kb)
#pragma unroll
            for (int r = 0; r < 4; ++r) pmax = fmaxf(pmax, st[kb][r]);
    }
    pmax = fmaxf(pmax, __shfl_xor(pmax, 16));
    pmax = fmaxf(pmax, __shfl_xor(pmax, 32));

    // deferred rescale (T13, THR=8): skip O-rescale while max grows by <= 8
    if (!__all(pmax <= mrun + 8.0f)) {
        const float mnew = fmaxf(mrun, pmax);
        const float scale = __expf(mrun - mnew);  // exp(-inf)=0 on first tile
        lrun *= scale;
        float scr[4];
#pragma unroll
        for (int r = 0; r < 4; ++r) scr[r] = __shfl(scale, g * 4 + r);
#pragma unroll
        for (int d = 0; d < 4; ++d)
#pragma unroll
            for (int r = 0; r < 4; ++r) yacc[d][r] *= scr[r];
        mrun = mnew;
    }

    float psum = 0.0f;
    v4s pw[4];
#pragma unroll
    for (int kb = 0; kb < 4; ++kb)
#pragma unroll
        for (int r = 0; r < 4; ++r) {
            const float pv = __expf(st[kb][r] - mrun);  // masked -> exp(-inf)=0
            psum += pv;
            pw[kb][r] = (short)f2bf(pv);
        }
    psum += __shfl_xor(psum, 16);
    psum += __shfl_xor(psum, 32);
    lrun += psum;

    // y += P * V (P fragments straight from registers)
#pragma unroll
    for (int ks = 0; ks < 4; ++ks) {
        if (diag && ks > w) continue;  // P==0 there
#pragma unroll
        for (int d = 0; d < 4; ++d) {
            const v4s vf = *(const v4s*)((const char*)Vt + (d * 16 + c16) * 136 + ks * 32 + 8 * g);
            yacc[d] = MFMA16(pw[ks], vf, yacc[d]);
        }
    }
}

// ---------------- causal attention: qkv bf16 [8192][2304] (k|q|v) -> y bf16 [8192][768]
// fold-paired: block p handles q-tiles qtA=15-p and qtB=p; K/V tiles staged ONCE.
__global__ __launch_bounds__(256) void attn_kernel(const unsigned short* __restrict__ qkv,
                                                   unsigned short* __restrict__ y) {
    __shared__ __align__(16) unsigned short Ks[64 * 64];  // swizzled [kk][d]
    __shared__ __align__(16) unsigned short Vt[64 * 68];  // [d][kk], stride 68
    const int tid = threadIdx.x;
    const int lane = tid & 63;
    const int w = tid >> 6;
    const int g = lane >> 4;
    const int c16 = lane & 15;
    const int p = blockIdx.x;  // 0..7
    const int h = blockIdx.y, b = blockIdx.z;
    const int qtA = 15 - p, qtB = p;
    const int tokA = b * 1024 + qtA * 64;
    const int tokB = b * 1024 + qtB * 64;

    v8s qfA[2], qfB[2];
    {
        const unsigned short* qbA = qkv + (size_t)(tokA + w * 16 + c16) * 2304 + 768 + h * 64;
        const unsigned short* qbB = qkv + (size_t)(tokB + w * 16 + c16) * 2304 + 768 + h * 64;
#pragma unroll
        for (int ks = 0; ks < 2; ++ks) {
            qfA[ks] = *(const v8s*)(qbA + ks * 32 + 8 * g);
            qfB[ks] = *(const v8s*)(qbB + ks * 32 + 8 * g);
        }
    }

    v4f yA[4], yB[4];
#pragma unroll
    for (int d = 0; d < 4; ++d) {
        yA[d] = (v4f){0.f, 0.f, 0.f, 0.f};
        yB[d] = (v4f){0.f, 0.f, 0.f, 0.f};
    }
    float mA = -__builtin_inff(), lA = 0.0f;
    float mB = -__builtin_inff(), lB = 0.0f;
    const int qrow = w * 16 + c16;  // my softmax column's row-in-tile

    for (int kt = 0; kt <= qtA; ++kt) {
        const int tokk = b * 1024 + kt * 64;
        __syncthreads();
        // stage K (swizzled) via global_load_lds: 512 chunks
#pragma unroll
        for (int i = 0; i < 2; ++i) {
            const int c = (i * 4 + w) * 64 + lane;
            const int kk = c >> 3;
            const int dc = (c & 7) ^ (kk & 7);
            gld16(qkv + (size_t)(tokk + kk) * 2304 + h * 64 + dc * 8, Ks + (size_t)c * 8);
        }
        // stage V transposed ([d][kk]) via registers
#pragma unroll
        for (int it = 0; it < 2; ++it) {
            const int off = (it * 256 + tid) * 8;
            const int kk = off >> 6, d0 = off & 63;
            us8 vv = *(const us8*)(qkv + (size_t)(tokk + kk) * 2304 + 1536 + h * 64 + d0);
#pragma unroll
            for (int j = 0; j < 8; ++j) Vt[(d0 + j) * 68 + kk] = vv[j];
        }
        __syncthreads();

        attn_tile(Ks, Vt, qfA, yA, mA, lA, kt == qtA, qrow, w, g, c16);
        if (kt <= qtB)
            attn_tile(Ks, Vt, qfB, yB, mB, lB, kt == qtB, qrow, w, g, c16);
    }

    {
        const float inv = 1.0f / lA;
        float invr[4];
#pragma unroll
        for (int r = 0; r < 4; ++r) invr[r] = __shfl(inv, g * 4 + r);
#pragma unroll
        for (int d = 0; d < 4; ++d)
#pragma unroll
            for (int r = 0; r < 4; ++r) {
                const int row = tokA + w * 16 + 4 * g + r;
                const int col = h * 64 + d * 16 + c16;
                y[(size_t)row * 768 + col] = f2bf(yA[d][r] * invr[r]);
            }
    }
    {
        const float inv = 1.0f / lB;
        float invr[4];
#pragma unroll
        for (int r = 0; r < 4; ++r) invr[r] = __shfl(inv, g * 4 + r);
#pragma unroll
        for (int d = 0; d < 4; ++d)
#pragma unroll
            for (int r = 0; r < 4; ++r) {
                const int row = tokB + w * 16 + 4 * g + r;
                const int col = h * 64 + d * 16 + c16;
                y[(size_t)row * 768 + col] = f2bf(yB[d][r] * invr[r]);
            }
    }
}

extern "C" void kernel_launch(void* const* d_in, const int* in_sizes, int n_in,
                              void* d_out, int out_size, void* d_ws, size_t ws_size,
                              hipStream_t stream) {
    const float* x = (const float*)d_in[0];
    const float* ln_w = (const float*)d_in[1];
    const float* ln_b = (const float*)d_in[2];
    const float* w_qkv = (const float*)d_in[3];
    const float* b_qkv = (const float*)d_in[4];
    const float* w_out = (const float*)d_in[5];
    const float* b_out = (const float*)d_in[6];
    const float* w_c1 = (const float*)d_in[7];
    const float* b_c1 = (const float*)d_in[8];
    const float* w_c2 = (const float*)d_in[9];
    const float* b_c2 = (const float*)d_in[10];
    float* out = (float*)d_out;

    char* ws = (char*)d_ws;
    unsigned short* wTqkv = (unsigned short*)(ws + 0);          // [2304][768]
    unsigned short* wTout = (unsigned short*)(ws + 3538944);    // [768][768]
    unsigned short* wTc1 = (unsigned short*)(ws + 4718592);     // [3072][768]
    unsigned short* wTc2 = (unsigned short*)(ws + 9437184);     // [768][3072]
    unsigned short* hbuf = (unsigned short*)(ws + 14155776);    // [8192][768] bf16 (h, then h2)
    unsigned short* qkvb = (unsigned short*)(ws + 26738688);    // [8192][2304] bf16
    unsigned short* ybuf = (unsigned short*)(ws + 64487424);    // [8192][768] bf16
    float* x2 = (float*)(ws + 77070336);                        // [8192][768] f32
    unsigned short* m1 = qkvb;  // reuse qkv+y region: [8192][3072] bf16

    transpose_cvt<<<dim3(2304 / 32, 768 / 32), 256, 0, stream>>>(w_qkv, wTqkv, 768, 2304);
    transpose_cvt<<<dim3(768 / 32, 768 / 32), 256, 0, stream>>>(w_out, wTout, 768, 768);
    transpose_cvt<<<dim3(3072 / 32, 768 / 32), 256, 0, stream>>>(w_c1, wTc1, 768, 3072);
    transpose_cvt<<<dim3(768 / 32, 3072 / 32), 256, 0, stream>>>(w_c2, wTc2, 3072, 768);

    ln_row<<<8192, 256, 0, stream>>>(x, ln_w, ln_b, hbuf);
    gemm_bf16<0><<<dim3(64, 18), 256, 0, stream>>>(hbuf, wTqkv, b_qkv, nullptr, qkvb, 8192, 2304, 768);
    attn_kernel<<<dim3(8, 12, 8), 256, 0, stream>>>(qkvb, ybuf);
    gemm_bf16<1><<<dim3(64, 6), 256, 0, stream>>>(ybuf, wTout, b_out, x, x2, 8192, 768, 768);
    ln_row<<<8192, 256, 0, stream>>>(x2, ln_w, ln_b, hbuf);
    gemm_bf16<2><<<dim3(64, 24), 256, 0, stream>>>(hbuf, wTc1, b_c1, nullptr, m1, 8192, 3072, 768);
    gemm_bf16<1><<<dim3(64, 6), 256, 0, stream>>>(m1, wTc2, b_c2, x2, out, 8192, 768, 3072);
}

// Round 9
// 333.191 us; speedup vs baseline: 1.2164x; 1.0538x over previous
//
#include <hip/hip_runtime.h>
#include <hip/hip_bf16.h>
#include <math.h>

typedef short v4s __attribute__((ext_vector_type(4)));
typedef short v8s __attribute__((ext_vector_type(8)));
typedef float v4f __attribute__((ext_vector_type(4)));
typedef unsigned short us8 __attribute__((ext_vector_type(8)));

#if __has_builtin(__builtin_amdgcn_mfma_f32_16x16x16bf16_1k)
#define MFMA16(a, b, c) __builtin_amdgcn_mfma_f32_16x16x16bf16_1k(a, b, c, 0, 0, 0)
#else
__device__ inline v4f mfma16_fb(v4s a, v4s b, v4f c) {
    v8s a8 = {a[0], a[1], a[2], a[3], 0, 0, 0, 0};
    v8s b8 = {b[0], b[1], b[2], b[3], 0, 0, 0, 0};
    return __builtin_amdgcn_mfma_f32_16x16x32_bf16(a8, b8, c, 0, 0, 0);
}
#define MFMA16(a, b, c) mfma16_fb(a, b, c)
#endif

#define MFMA32(a, b, c) __builtin_amdgcn_mfma_f32_16x16x32_bf16(a, b, c, 0, 0, 0)

__device__ inline unsigned short f2bf(float f) {
    __hip_bfloat16 h = __float2bfloat16(f);
    union { __hip_bfloat16 h; unsigned short u; } cv;
    cv.h = h;
    return cv.u;
}

__device__ inline void gld16(const void* g, void* l) {
    __builtin_amdgcn_global_load_lds((const __attribute__((address_space(1))) void*)g,
                                     (__attribute__((address_space(3))) void*)l, 16, 0, 0);
}

// fast GELU (tanh form via sigmoid): max abs err vs exact-erf gelu ~1e-3
__device__ inline float gelu_fast(float v) {
    const float z2 = 1.5957691216057308f * (v + 0.044715f * v * v * v);
    return v / (1.0f + __expf(-z2));
}

// ---------------- weight transpose + bf16 convert: in f32 [R][Cn] -> out bf16 [Cn][R]
__global__ __launch_bounds__(256) void transpose_cvt(const float* __restrict__ in,
                                                     unsigned short* __restrict__ out,
                                                     int R, int Cn) {
    __shared__ float t[32][33];
    const int tid = threadIdx.x;
    const int tx = tid & 31, ty = tid >> 5;
    const int bx = blockIdx.x, by = blockIdx.y;
#pragma unroll
    for (int i = 0; i < 4; ++i) {
        int r = by * 32 + ty + i * 8;
        int c = bx * 32 + tx;
        t[ty + i * 8][tx] = in[(size_t)r * Cn + c];
    }
    __syncthreads();
#pragma unroll
    for (int i = 0; i < 4; ++i) {
        out[(size_t)(bx * 32 + ty + i * 8) * R + by * 32 + tx] = f2bf(t[tx][ty + i * 8]);
    }
}

// ---------------- LayerNorm row kernel: f32 [rows][768] -> bf16 [rows][768]
__global__ __launch_bounds__(256) void ln_row(const float* __restrict__ x,
                                              const float* __restrict__ lw,
                                              const float* __restrict__ lb,
                                              unsigned short* __restrict__ out) {
    const int row = blockIdx.x;
    const int tid = threadIdx.x;
    const float* xr = x + (size_t)row * 768;
    float v0 = xr[tid], v1 = xr[tid + 256], v2 = xr[tid + 512];
    float s = v0 + v1 + v2;
    float q = v0 * v0 + v1 * v1 + v2 * v2;
#pragma unroll
    for (int o = 1; o < 64; o <<= 1) {
        s += __shfl_xor(s, o);
        q += __shfl_xor(q, o);
    }
    __shared__ float rs[4], rq[4];
    const int w = tid >> 6;
    if ((tid & 63) == 0) { rs[w] = s; rq[w] = q; }
    __syncthreads();
    s = rs[0] + rs[1] + rs[2] + rs[3];
    q = rq[0] + rq[1] + rq[2] + rq[3];
    const float mean = s * (1.0f / 768.0f);
    const float var = q * (1.0f / 768.0f) - mean * mean;
    const float rstd = rsqrtf(var + 1e-5f);
    unsigned short* orow = out + (size_t)row * 768;
    orow[tid] = f2bf((v0 - mean) * rstd * lw[tid] + lb[tid]);
    orow[tid + 256] = f2bf((v1 - mean) * rstd * lw[tid + 256] + lb[tid + 256]);
    orow[tid + 512] = f2bf((v2 - mean) * rstd * lw[tid + 512] + lb[tid + 512]);
}

// ---------------- GEMM: out[M][N] = A[M][K] * BT[N][K]^T + bias (+resid) (+gelu)
// EPI 0: bias -> bf16 ; EPI 1: bias + resid -> f32 ; EPI 2: bias + gelu -> bf16
// BN: 128 (4 waves x 64x64, acc[4][4]) or 64 (4 waves x 64x32, acc[4][2]) —
// BN=64 exists to fix grid quantization for N=768 outputs (768 blocks = 3.0/CU).
template <int EPI, int BN>
__global__ __launch_bounds__(256) void gemm_bf16(const unsigned short* __restrict__ A,
                                                 const unsigned short* __restrict__ BT,
                                                 const float* __restrict__ bias,
                                                 const float* __restrict__ resid,
                                                 void* __restrict__ outp,
                                                 int M, int N, int K) {
    constexpr int NB = BN / 32;   // B-frags per wave (4 or 2)
    constexpr int NBI = BN / 32;  // B staging iterations (4 or 2)
    __shared__ __align__(16) unsigned short As[128 * 64];
    __shared__ __align__(16) unsigned short Bs[BN * 64];
    const int tid = threadIdx.x;
    const int lane = tid & 63;
    const int w = tid >> 6;
    const int g = lane >> 4;
    const int c16 = lane & 15;
    const int row0 = blockIdx.x * 128;
    const int col0 = blockIdx.y * BN;
    const int wm = w & 1, wn = w >> 1;

    v4f acc[4][NB];
#pragma unroll
    for (int m = 0; m < 4; ++m)
#pragma unroll
        for (int n = 0; n < NB; ++n) acc[m][n] = (v4f){0.f, 0.f, 0.f, 0.f};

    const unsigned short* ap[4];
    const unsigned short* bp[NBI];
#pragma unroll
    for (int i = 0; i < 4; ++i) {
        const int c = (i * 4 + w) * 64 + lane;  // 16B chunk id
        const int r = c >> 3;
        const int dc = (c & 7) ^ (r & 7);  // XOR-swizzled source chunk
        ap[i] = A + (size_t)(row0 + r) * K + dc * 8;
    }
#pragma unroll
    for (int i = 0; i < NBI; ++i) {
        const int c = (i * 4 + w) * 64 + lane;
        const int r = c >> 3;
        const int dc = (c & 7) ^ (r & 7);
        bp[i] = BT + (size_t)(col0 + r) * K + dc * 8;
    }

    const int nk = K >> 6;
    for (int kt = 0; kt < nk; ++kt) {
        __syncthreads();  // protect previous-iteration reads
#pragma unroll
        for (int i = 0; i < 4; ++i) {
            const int c = (i * 4 + w) * 64 + lane;
            gld16(ap[i], As + (size_t)c * 8);
            ap[i] += 64;
        }
#pragma unroll
        for (int i = 0; i < NBI; ++i) {
            const int c = (i * 4 + w) * 64 + lane;
            gld16(bp[i], Bs + (size_t)c * 8);
            bp[i] += 64;
        }
        __syncthreads();  // drains vmcnt before barrier
#pragma unroll
        for (int ks = 0; ks < 2; ++ks) {
            const int koff = ks * 64 + 16 * g;  // byte offset of this lane's 16B chunk
            v8s af[4], bf[NB];
#pragma unroll
            for (int m = 0; m < 4; ++m) {
                const int r = wm * 64 + m * 16 + c16;
                af[m] = *(const v8s*)((const char*)As + r * 128 + (koff ^ ((r & 7) << 4)));
            }
#pragma unroll
            for (int n = 0; n < NB; ++n) {
                const int r = wn * (BN / 2) + n * 16 + c16;
                bf[n] = *(const v8s*)((const char*)Bs + r * 128 + (koff ^ ((r & 7) << 4)));
            }
#pragma unroll
            for (int m = 0; m < 4; ++m)
#pragma unroll
                for (int n = 0; n < NB; ++n) acc[m][n] = MFMA32(af[m], bf[n], acc[m][n]);
        }
    }
#pragma unroll
    for (int m = 0; m < 4; ++m)
#pragma unroll
        for (int n = 0; n < NB; ++n)
#pragma unroll
            for (int r = 0; r < 4; ++r) {
                const int row = row0 + wm * 64 + m * 16 + 4 * g + r;
                const int col = col0 + wn * (BN / 2) + n * 16 + c16;
                float v = acc[m][n][r] + bias[col];
                if (EPI == 1) v += resid[(size_t)row * N + col];
                if (EPI == 2) v = gelu_fast(v);
                if (EPI == 1)
                    ((float*)outp)[(size_t)row * N + col] = v;
                else
                    ((unsigned short*)outp)[(size_t)row * N + col] = f2bf(v);
            }
}

// ---------------- attention tile compute: S^T = K*Q^T (x32), online softmax, y += P*V
// P stays in registers: lane (c16,g) holds P[q=c16][k=kb*16+4g+r] which IS the x16 PV
// A-fragment (A[row=l&15][k=4g+j]). No LDS round-trip for P.
__device__ inline void attn_tile(const unsigned short* Ks, const unsigned short* Vt,
                                 const v8s* qf8, v4f* yacc,
                                 float& mrun, float& lrun, bool diag, int qrow,
                                 int w, int g, int c16) {
    v4f st[4];
#pragma unroll
    for (int kb = 0; kb < 4; ++kb) st[kb] = (v4f){0.f, 0.f, 0.f, 0.f};
#pragma unroll
    for (int ks = 0; ks < 2; ++ks) {
        const int koff = ks * 64 + 16 * g;
#pragma unroll
        for (int kb = 0; kb < 4; ++kb) {
            if (diag && kb > w) continue;  // fully-masked 16-row block on diagonal tile
            const int r = kb * 16 + c16;
            const v8s kf = *(const v8s*)((const char*)Ks + r * 128 + (koff ^ ((r & 7) << 4)));
            st[kb] = MFMA32(kf, qf8[ks], st[kb]);
        }
    }

    float pmax = -__builtin_inff();
    if (diag) {
#pragma unroll
        for (int kb = 0; kb < 4; ++kb)
#pragma unroll
            for (int r = 0; r < 4; ++r) {
                if (kb > w || kb * 16 + 4 * g + r > qrow) st[kb][r] = -__builtin_inff();
                pmax = fmaxf(pmax, st[kb][r]);
            }
    } else {
#pragma unroll
        for (int kb = 0; kb < 4; ++kb)
#pragma unroll
            for (int r = 0; r < 4; ++r) pmax = fmaxf(pmax, st[kb][r]);
    }
    pmax = fmaxf(pmax, __shfl_xor(pmax, 16));
    pmax = fmaxf(pmax, __shfl_xor(pmax, 32));

    // deferred rescale (T13, THR=8): skip O-rescale while max grows by <= 8
    if (!__all(pmax <= mrun + 8.0f)) {
        const float mnew = fmaxf(mrun, pmax);
        const float scale = __expf(mrun - mnew);  // exp(-inf)=0 on first tile
        lrun *= scale;
        float scr[4];
#pragma unroll
        for (int r = 0; r < 4; ++r) scr[r] = __shfl(scale, g * 4 + r);
#pragma unroll
        for (int d = 0; d < 4; ++d)
#pragma unroll
            for (int r = 0; r < 4; ++r) yacc[d][r] *= scr[r];
        mrun = mnew;
    }

    float psum = 0.0f;
    v4s pw[4];
#pragma unroll
    for (int kb = 0; kb < 4; ++kb)
#pragma unroll
        for (int r = 0; r < 4; ++r) {
            const float pv = __expf(st[kb][r] - mrun);  // masked -> exp(-inf)=0
            psum += pv;
            pw[kb][r] = (short)f2bf(pv);
        }
    psum += __shfl_xor(psum, 16);
    psum += __shfl_xor(psum, 32);
    lrun += psum;

    // y += P * V (P fragments straight from registers)
#pragma unroll
    for (int ks = 0; ks < 4; ++ks) {
        if (diag && ks > w) continue;  // P==0 there
#pragma unroll
        for (int d = 0; d < 4; ++d) {
            const v4s vf = *(const v4s*)((const char*)Vt + (d * 16 + c16) * 136 + ks * 32 + 8 * g);
            yacc[d] = MFMA16(pw[ks], vf, yacc[d]);
        }
    }
}

// ---------------- causal attention: qkv bf16 [8192][2304] (k|q|v) -> y bf16 [8192][768]
// fold-paired: block p handles q-tiles qtA=15-p and qtB=p; K/V tiles staged ONCE.
__global__ __launch_bounds__(256) void attn_kernel(const unsigned short* __restrict__ qkv,
                                                   unsigned short* __restrict__ y) {
    __shared__ __align__(16) unsigned short Ks[64 * 64];  // swizzled [kk][d]
    __shared__ __align__(16) unsigned short Vt[64 * 68];  // [d][kk], stride 68
    const int tid = threadIdx.x;
    const int lane = tid & 63;
    const int w = tid >> 6;
    const int g = lane >> 4;
    const int c16 = lane & 15;
    const int p = blockIdx.x;  // 0..7
    const int h = blockIdx.y, b = blockIdx.z;
    const int qtA = 15 - p, qtB = p;
    const int tokA = b * 1024 + qtA * 64;
    const int tokB = b * 1024 + qtB * 64;

    v8s qfA[2], qfB[2];
    {
        const unsigned short* qbA = qkv + (size_t)(tokA + w * 16 + c16) * 2304 + 768 + h * 64;
        const unsigned short* qbB = qkv + (size_t)(tokB + w * 16 + c16) * 2304 + 768 + h * 64;
#pragma unroll
        for (int ks = 0; ks < 2; ++ks) {
            qfA[ks] = *(const v8s*)(qbA + ks * 32 + 8 * g);
            qfB[ks] = *(const v8s*)(qbB + ks * 32 + 8 * g);
        }
    }

    v4f yA[4], yB[4];
#pragma unroll
    for (int d = 0; d < 4; ++d) {
        yA[d] = (v4f){0.f, 0.f, 0.f, 0.f};
        yB[d] = (v4f){0.f, 0.f, 0.f, 0.f};
    }
    float mA = -__builtin_inff(), lA = 0.0f;
    float mB = -__builtin_inff(), lB = 0.0f;
    const int qrow = w * 16 + c16;  // my softmax column's row-in-tile

    for (int kt = 0; kt <= qtA; ++kt) {
        const int tokk = b * 1024 + kt * 64;
        __syncthreads();
        // stage K (swizzled) via global_load_lds: 512 chunks
#pragma unroll
        for (int i = 0; i < 2; ++i) {
            const int c = (i * 4 + w) * 64 + lane;
            const int kk = c >> 3;
            const int dc = (c & 7) ^ (kk & 7);
            gld16(qkv + (size_t)(tokk + kk) * 2304 + h * 64 + dc * 8, Ks + (size_t)c * 8);
        }
        // stage V transposed ([d][kk]) via registers
#pragma unroll
        for (int it = 0; it < 2; ++it) {
            const int off = (it * 256 + tid) * 8;
            const int kk = off >> 6, d0 = off & 63;
            us8 vv = *(const us8*)(qkv + (size_t)(tokk + kk) * 2304 + 1536 + h * 64 + d0);
#pragma unroll
            for (int j = 0; j < 8; ++j) Vt[(d0 + j) * 68 + kk] = vv[j];
        }
        __syncthreads();

        attn_tile(Ks, Vt, qfA, yA, mA, lA, kt == qtA, qrow, w, g, c16);
        if (kt <= qtB)
            attn_tile(Ks, Vt, qfB, yB, mB, lB, kt == qtB, qrow, w, g, c16);
    }

    {
        const float inv = 1.0f / lA;
        float invr[4];
#pragma unroll
        for (int r = 0; r < 4; ++r) invr[r] = __shfl(inv, g * 4 + r);
#pragma unroll
        for (int d = 0; d < 4; ++d)
#pragma unroll
            for (int r = 0; r < 4; ++r) {
                const int row = tokA + w * 16 + 4 * g + r;
                const int col = h * 64 + d * 16 + c16;
                y[(size_t)row * 768 + col] = f2bf(yA[d][r] * invr[r]);
            }
    }
    {
        const float inv = 1.0f / lB;
        float invr[4];
#pragma unroll
        for (int r = 0; r < 4; ++r) invr[r] = __shfl(inv, g * 4 + r);
#pragma unroll
        for (int d = 0; d < 4; ++d)
#pragma unroll
            for (int r = 0; r < 4; ++r) {
                const int row = tokB + w * 16 + 4 * g + r;
                const int col = h * 64 + d * 16 + c16;
                y[(size_t)row * 768 + col] = f2bf(yB[d][r] * invr[r]);
            }
    }
}

extern "C" void kernel_launch(void* const* d_in, const int* in_sizes, int n_in,
                              void* d_out, int out_size, void* d_ws, size_t ws_size,
                              hipStream_t stream) {
    const float* x = (const float*)d_in[0];
    const float* ln_w = (const float*)d_in[1];
    const float* ln_b = (const float*)d_in[2];
    const float* w_qkv = (const float*)d_in[3];
    const float* b_qkv = (const float*)d_in[4];
    const float* w_out = (const float*)d_in[5];
    const float* b_out = (const float*)d_in[6];
    const float* w_c1 = (const float*)d_in[7];
    const float* b_c1 = (const float*)d_in[8];
    const float* w_c2 = (const float*)d_in[9];
    const float* b_c2 = (const float*)d_in[10];
    float* out = (float*)d_out;

    char* ws = (char*)d_ws;
    unsigned short* wTqkv = (unsigned short*)(ws + 0);          // [2304][768]
    unsigned short* wTout = (unsigned short*)(ws + 3538944);    // [768][768]
    unsigned short* wTc1 = (unsigned short*)(ws + 4718592);     // [3072][768]
    unsigned short* wTc2 = (unsigned short*)(ws + 9437184);     // [768][3072]
    unsigned short* hbuf = (unsigned short*)(ws + 14155776);    // [8192][768] bf16 (h, then h2)
    unsigned short* qkvb = (unsigned short*)(ws + 26738688);    // [8192][2304] bf16
    unsigned short* ybuf = (unsigned short*)(ws + 64487424);    // [8192][768] bf16
    float* x2 = (float*)(ws + 77070336);                        // [8192][768] f32
    unsigned short* m1 = qkvb;  // reuse qkv+y region: [8192][3072] bf16

    transpose_cvt<<<dim3(2304 / 32, 768 / 32), 256, 0, stream>>>(w_qkv, wTqkv, 768, 2304);
    transpose_cvt<<<dim3(768 / 32, 768 / 32), 256, 0, stream>>>(w_out, wTout, 768, 768);
    transpose_cvt<<<dim3(3072 / 32, 768 / 32), 256, 0, stream>>>(w_c1, wTc1, 768, 3072);
    transpose_cvt<<<dim3(768 / 32, 3072 / 32), 256, 0, stream>>>(w_c2, wTc2, 3072, 768);

    ln_row<<<8192, 256, 0, stream>>>(x, ln_w, ln_b, hbuf);
    gemm_bf16<0, 128><<<dim3(64, 18), 256, 0, stream>>>(hbuf, wTqkv, b_qkv, nullptr, qkvb, 8192, 2304, 768);
    attn_kernel<<<dim3(8, 12, 8), 256, 0, stream>>>(qkvb, ybuf);
    gemm_bf16<1, 64><<<dim3(64, 12), 256, 0, stream>>>(ybuf, wTout, b_out, x, x2, 8192, 768, 768);
    ln_row<<<8192, 256, 0, stream>>>(x2, ln_w, ln_b, hbuf);
    gemm_bf16<2, 128><<<dim3(64, 24), 256, 0, stream>>>(hbuf, wTc1, b_c1, nullptr, m1, 8192, 3072, 768);
    gemm_bf16<1, 64><<<dim3(64, 12), 256, 0, stream>>>(m1, wTc2, b_c2, x2, out, 8192, 768, 3072);
}